// Round 2
// baseline (207.682 us; speedup 1.0000x reference)
//
#include <hip/hip_runtime.h>

// CustomGraphConv (fp32 in/out, int64 edge_index runtime-detected):
//   msg[e,o] = sum_{a,i} ea[e,a]*W[a,o,i]*x[src_e,i]; scatter-add to dst; relu(+bias).
//
// Structure (R6-derived; R7 proved CSR/sort loses to atomics on this HW):
//   stage1: y[n,o,a] = sum_i W[a,o,i]*x[n,i]  (bf16, 25.6 MB, L3-resident)
//           + zero-tail blocks clear the two bf16 accumulators (memset folded in).
//   stage2: 8 lanes/edge-pair; lane q computes channels {2q,2q+1} for TWO edges
//           (e, e+E/2) via dot8 against y[src], packs bf16x2, one
//           global_atomic_pk_add_bf16 per edge -> 12.8M lane-ops.
//           ei/ea loads are NON-TEMPORAL (no L2 allocate) so the 77 MB stream
//           stops evicting the y table (25.6 MB, wants L2 residency; measured
//           69% hit -> predict ~90%). 2 edges/thread = 2 independent
//           ei->y->atomic chains per wave (latency-bound per R8 counters).
//           Accumulation split across two bf16 buffers by edge parity to halve
//           the bf16 running-sum rounding walk.
//   final:  out = relu(f32(bufA) + f32(bufB) + bias), single write of d_out.

#define IN_C 16
#define OUT_C 16
#define NA 8

typedef unsigned short u16;
typedef unsigned int u32;
typedef short v2s __attribute__((ext_vector_type(2)));
typedef float v4f __attribute__((ext_vector_type(4)));

__device__ __forceinline__ float bfbits(u32 hi) {
    union { u32 u; float f; } c; c.u = hi; return c.f;
}
__device__ __forceinline__ u16 f2bf(float f) {
    union { float f; u32 u; } c; c.f = f;
    u32 u = c.u + (0x7fffu + ((c.u >> 16) & 1u));   // RNE
    return (u16)(u >> 16);
}
__device__ __forceinline__ float dot4(float4 a, float4 b) {
    float s = a.x * b.x;
    s = fmaf(a.y, b.y, s); s = fmaf(a.z, b.z, s); s = fmaf(a.w, b.w, s);
    return s;
}
__device__ __forceinline__ float dot8y(uint4 yu, v4f a0, v4f a1) {
    float s = bfbits(yu.x << 16) * a0.x;
    s = fmaf(bfbits(yu.x & 0xffff0000u), a0.y, s);
    s = fmaf(bfbits(yu.y << 16),         a0.z, s);
    s = fmaf(bfbits(yu.y & 0xffff0000u), a0.w, s);
    s = fmaf(bfbits(yu.z << 16),         a1.x, s);
    s = fmaf(bfbits(yu.z & 0xffff0000u), a1.y, s);
    s = fmaf(bfbits(yu.w << 16),         a1.z, s);
    s = fmaf(bfbits(yu.w & 0xffff0000u), a1.w, s);
    return s;
}

// ---------- stage 1: y_bf16[n][o][a] = dot(W[a,o,:], x[n,:]), 2 nodes/thread;
//            zeroes out[]; block 0 detects int64; tail blocks zero the
//            bf16 accumulators (replaces hipMemsetAsync dispatch) ----------
__global__ void __launch_bounds__(256) k_stage1(
    const float* __restrict__ x, const float* __restrict__ W,
    const int* __restrict__ ei, long long n_edges,
    u16* __restrict__ y, float* __restrict__ out,
    int* __restrict__ flag, int n_nodes,
    int main_blocks, uint4* __restrict__ zbase, int zcnt) {
    if ((int)blockIdx.x >= main_blocks) {
        int zi = ((int)blockIdx.x - main_blocks) * 256 + (int)threadIdx.x;
        if (zi < zcnt) { uint4 z; z.x = z.y = z.z = z.w = 0u; zbase[zi] = z; }
        return;
    }
    __shared__ int s_nz;
    if (blockIdx.x == 0) {
        if (threadIdx.x == 0) s_nz = 0;
        __syncthreads();
        long long step = (n_edges / 256) | 1;
        long long pos = 1 + 2 * (long long)threadIdx.x * step;
        if (pos < 2 * n_edges && ei[pos] != 0) atomicOr(&s_nz, 1);
        __syncthreads();
        if (threadIdx.x == 0) flag[0] = (s_nz == 0) ? 1 : 0;   // 1 => int64
    }
    __shared__ float4 Wl[OUT_C][33];
    for (int k = threadIdx.x; k < 512; k += 256) {
        int a = k >> 6, o = (k >> 2) & 15, q = k & 3;
        Wl[o][a * 4 + q] = reinterpret_cast<const float4*>(W)[k];
    }
    __syncthreads();
    int npairs = (n_nodes + 1) >> 1;
    int idx = blockIdx.x * 256 + threadIdx.x;
    if (idx >= npairs * OUT_C) return;
    int p = idx >> 4, o = idx & 15;
    int n0 = p * 2;
    bool has1 = (n0 + 1) < n_nodes;
    const float4* xp0 = reinterpret_cast<const float4*>(x + (size_t)n0 * IN_C);
    float4 X0[4] = {xp0[0], xp0[1], xp0[2], xp0[3]};
    float4 X1[4];
    if (has1) {
        const float4* xp1 = reinterpret_cast<const float4*>(x + (size_t)(n0 + 1) * IN_C);
        X1[0] = xp1[0]; X1[1] = xp1[1]; X1[2] = xp1[2]; X1[3] = xp1[3];
    }
    union { uint4 u; u16 h[8]; } pk0, pk1;
#pragma unroll
    for (int a = 0; a < NA; ++a) {
        float4 w0 = Wl[o][a * 4 + 0], w1 = Wl[o][a * 4 + 1];
        float4 w2 = Wl[o][a * 4 + 2], w3 = Wl[o][a * 4 + 3];
        float s0 = dot4(w0, X0[0]) + dot4(w1, X0[1]) + dot4(w2, X0[2]) + dot4(w3, X0[3]);
        pk0.h[a] = f2bf(s0);
        if (has1) {
            float s1 = dot4(w0, X1[0]) + dot4(w1, X1[1]) + dot4(w2, X1[2]) + dot4(w3, X1[3]);
            pk1.h[a] = f2bf(s1);
        }
    }
    reinterpret_cast<uint4*>(y + ((size_t)n0 * OUT_C + o) * NA)[0] = pk0.u;
    out[(size_t)n0 * OUT_C + o] = 0.f;
    if (has1) {
        reinterpret_cast<uint4*>(y + ((size_t)(n0 + 1) * OUT_C + o) * NA)[0] = pk1.u;
        out[(size_t)(n0 + 1) * OUT_C + o] = 0.f;
    }
}

// ---------- stage 2 (pk-bf16): 8 lanes x 2 edges per thread, lane q ->
//            channels 2q,2q+1; nontemporal ei/ea (keep y in L2);
//            one packed-bf16 atomic per edge; edge-parity buffer split ----------
__global__ void __launch_bounds__(256) k_stage2_pk(
    const int* __restrict__ ei, const float* __restrict__ ea,
    const u16* __restrict__ y, u16* __restrict__ bufA, u16* __restrict__ bufB,
    const int* __restrict__ flag, long long n_edges) {
    long long half = (n_edges + 1) >> 1;
    long long gid = (long long)blockIdx.x * 256 + threadIdx.x;
    if (gid >= half * 8) return;
    long long p = gid >> 3;              // edge pair id: edges p and p+half
    int q = (int)(gid & 7);              // channel pair: 2q, 2q+1
    long long e1 = p + half;
    bool has1 = e1 < n_edges;
    int s0, d0, s1 = 0, d1 = 0;
    if (flag[0]) {                       // int64: low words at stride 2
        s0 = __builtin_nontemporal_load(ei + 2 * p);
        d0 = __builtin_nontemporal_load(ei + 2 * (n_edges + p));
        if (has1) {
            s1 = __builtin_nontemporal_load(ei + 2 * e1);
            d1 = __builtin_nontemporal_load(ei + 2 * (n_edges + e1));
        }
    } else {
        s0 = __builtin_nontemporal_load(ei + p);
        d0 = __builtin_nontemporal_load(ei + n_edges + p);
        if (has1) {
            s1 = __builtin_nontemporal_load(ei + e1);
            d1 = __builtin_nontemporal_load(ei + n_edges + e1);
        }
    }

    const v4f* ap0 = reinterpret_cast<const v4f*>(ea + p * NA);
    v4f a00 = __builtin_nontemporal_load(ap0);
    v4f a01 = __builtin_nontemporal_load(ap0 + 1);
    // y rows for channels 2q and 2q+1: 32 B contiguous; lanes q=0..7 tile the 256 B row.
    const uint4* yp0 = reinterpret_cast<const uint4*>(y + ((size_t)s0 * OUT_C + 2 * q) * NA);
    uint4 y00 = yp0[0], y01 = yp0[1];

    v4f a10, a11; uint4 y10, y11;
    if (has1) {
        const v4f* ap1 = reinterpret_cast<const v4f*>(ea + e1 * NA);
        a10 = __builtin_nontemporal_load(ap1);
        a11 = __builtin_nontemporal_load(ap1 + 1);
        const uint4* yp1 = reinterpret_cast<const uint4*>(y + ((size_t)s1 * OUT_C + 2 * q) * NA);
        y10 = yp1[0]; y11 = yp1[1];
    }

    union { v2s v; u16 h[2]; } pk0;
    pk0.h[0] = f2bf(dot8y(y00, a00, a01));
    pk0.h[1] = f2bf(dot8y(y01, a00, a01));
    u16* t0 = (p & 1) ? bufB : bufA;
    __builtin_amdgcn_global_atomic_fadd_v2bf16(
        reinterpret_cast<v2s*>(t0 + (size_t)d0 * OUT_C + 2 * q), pk0.v);

    if (has1) {
        union { v2s v; u16 h[2]; } pk1;
        pk1.h[0] = f2bf(dot8y(y10, a10, a11));
        pk1.h[1] = f2bf(dot8y(y11, a10, a11));
        u16* t1 = (e1 & 1) ? bufB : bufA;   // half is even for even E -> same parity as p
        __builtin_amdgcn_global_atomic_fadd_v2bf16(
            reinterpret_cast<v2s*>(t1 + (size_t)d1 * OUT_C + 2 * q), pk1.v);
    }
}

// ---------- final (pk path): out = relu(f32(bufA)+f32(bufB)+bias), 8 ch/thread ----------
__global__ void __launch_bounds__(256) k_final_pk(
    const u16* __restrict__ bufA, const u16* __restrict__ bufB,
    const float* __restrict__ bias, float* __restrict__ out, int total8) {
    int idx = blockIdx.x * 256 + threadIdx.x;
    if (idx >= total8) return;
    uint4 ua = reinterpret_cast<const uint4*>(bufA)[idx];
    uint4 ub = reinterpret_cast<const uint4*>(bufB)[idx];
    int ob = (idx & 1) * 8;
    const float4 b0 = reinterpret_cast<const float4*>(bias + ob)[0];
    const float4 b1 = reinterpret_cast<const float4*>(bias + ob + 4)[0];
    float fa[8], fb[8];
    u32 au[4] = {ua.x, ua.y, ua.z, ua.w}, bu[4] = {ub.x, ub.y, ub.z, ub.w};
#pragma unroll
    for (int j = 0; j < 4; ++j) {
        fa[2 * j]     = bfbits(au[j] << 16);
        fa[2 * j + 1] = bfbits(au[j] & 0xffff0000u);
        fb[2 * j]     = bfbits(bu[j] << 16);
        fb[2 * j + 1] = bfbits(bu[j] & 0xffff0000u);
    }
    float bb[8] = {b0.x, b0.y, b0.z, b0.w, b1.x, b1.y, b1.z, b1.w};
    float4 o0, o1;
    o0.x = fmaxf(fa[0] + fb[0] + bb[0], 0.f);
    o0.y = fmaxf(fa[1] + fb[1] + bb[1], 0.f);
    o0.z = fmaxf(fa[2] + fb[2] + bb[2], 0.f);
    o0.w = fmaxf(fa[3] + fb[3] + bb[3], 0.f);
    o1.x = fmaxf(fa[4] + fb[4] + bb[4], 0.f);
    o1.y = fmaxf(fa[5] + fb[5] + bb[5], 0.f);
    o1.z = fmaxf(fa[6] + fb[6] + bb[6], 0.f);
    o1.w = fmaxf(fa[7] + fb[7] + bb[7], 0.f);
    float4* op = reinterpret_cast<float4*>(out) + (size_t)idx * 2;
    op[0] = o0;
    op[1] = o1;
}

// ---------- fallback stage 2 (R6-proven): 16 lanes/edge, f32 atomics ----------
__global__ void __launch_bounds__(256) k_stage2(
    const int* __restrict__ ei, const float* __restrict__ ea,
    const u16* __restrict__ y, float* __restrict__ out,
    const int* __restrict__ flag, long long n_edges) {
    long long idx = (long long)blockIdx.x * 256 + threadIdx.x;
    if (idx >= n_edges * OUT_C) return;
    long long e = idx >> 4;
    int o = (int)(idx & 15);
    int src, dst;
    if (flag[0]) { src = ei[2 * e]; dst = ei[2 * (n_edges + e)]; }
    else         { src = ei[e];     dst = ei[n_edges + e]; }
    const float4* ap = reinterpret_cast<const float4*>(ea + e * NA);
    float4 af0 = ap[0], af1 = ap[1];
    v4f a0 = {af0.x, af0.y, af0.z, af0.w};
    v4f a1 = {af1.x, af1.y, af1.z, af1.w};
    uint4 yu = reinterpret_cast<const uint4*>(y + ((size_t)src * OUT_C + o) * NA)[0];
    float s = dot8y(yu, a0, a1);
    unsafeAtomicAdd(out + (size_t)dst * OUT_C + o, s);
}

__global__ void __launch_bounds__(256) k_bias_relu(
    const float* __restrict__ bias, float* __restrict__ out, int total4) {
    int idx = blockIdx.x * 256 + threadIdx.x;
    if (idx >= total4) return;
    int j0 = (idx & 3) * 4;
    const float4 b = reinterpret_cast<const float4*>(bias + j0)[0];
    float4* op = reinterpret_cast<float4*>(out) + idx;
    float4 v = op[0];
    v.x = fmaxf(v.x + b.x, 0.f);
    v.y = fmaxf(v.y + b.y, 0.f);
    v.z = fmaxf(v.z + b.z, 0.f);
    v.w = fmaxf(v.w + b.w, 0.f);
    op[0] = v;
}

// ---------- ultimate fallback (tiny ws): direct einsum, f32 atomics ----------
__global__ void __launch_bounds__(256) k_direct(
    const float* __restrict__ x, const int* __restrict__ ei,
    const float* __restrict__ ea, const float* __restrict__ W,
    float* __restrict__ out, long long n_edges) {
    __shared__ float Wl[OUT_C][129];
    for (int k = threadIdx.x; k < NA * OUT_C * IN_C; k += 256) {
        int a = k >> 8, o = (k >> 4) & 15, i = k & 15;
        Wl[o][a * IN_C + i] = W[k];
    }
    __syncthreads();
    long long idx = (long long)blockIdx.x * 256 + threadIdx.x;
    if (idx >= n_edges * OUT_C) return;
    long long e = idx >> 4;
    int o = (int)(idx & 15);
    int src = ei[2 * e], dst = ei[2 * (n_edges + e)];
    const float4* ap = reinterpret_cast<const float4*>(ea + e * NA);
    float4 a0 = ap[0], a1 = ap[1];
    float av[NA] = {a0.x, a0.y, a0.z, a0.w, a1.x, a1.y, a1.z, a1.w};
    const float4* xp = reinterpret_cast<const float4*>(x + (size_t)src * IN_C);
    float4 x0 = xp[0], x1 = xp[1], x2 = xp[2], x3 = xp[3];
    float xv[16] = {x0.x, x0.y, x0.z, x0.w, x1.x, x1.y, x1.z, x1.w,
                    x2.x, x2.y, x2.z, x2.w, x3.x, x3.y, x3.z, x3.w};
    float s = 0.f;
#pragma unroll
    for (int a = 0; a < NA; ++a) {
        float d = 0.f;
#pragma unroll
        for (int i = 0; i < IN_C; ++i) d = fmaf(Wl[o][a * IN_C + i], xv[i], d);
        s = fmaf(av[a], d, s);
    }
    unsafeAtomicAdd(out + (size_t)dst * OUT_C + o, s);
}

static inline size_t a256(size_t v) { return (v + 255) & ~(size_t)255; }

extern "C" void kernel_launch(void* const* d_in, const int* in_sizes, int n_in,
                              void* d_out, int out_size, void* d_ws, size_t ws_size,
                              hipStream_t stream) {
    const float* x    = (const float*)d_in[0];   // [N,16] f32
    const int*   ei   = (const int*)d_in[1];     // [2,E] int64/int32 (runtime-detected)
    const float* ea   = (const float*)d_in[2];   // [E,8] f32
    const float* W    = (const float*)d_in[3];   // [8,16,16] f32
    const float* bias = (const float*)d_in[4];   // [16] f32
    float* out = (float*)d_out;

    int n_nodes = in_sizes[0] / IN_C;
    long long E = in_sizes[2] / NA;

    size_t o_flag = 0;
    size_t o_y    = 256;
    size_t y_bytes = (size_t)n_nodes * OUT_C * NA * sizeof(u16);    // 25.6 MB
    size_t o_bufA = o_y + a256(y_bytes);
    size_t buf_bytes = (size_t)n_nodes * OUT_C * sizeof(u16);       // 3.2 MB each
    size_t o_bufB = o_bufA + a256(buf_bytes);
    size_t total_pk = o_bufB + a256(buf_bytes);                     // ~32.1 MB

    int npairs = (n_nodes + 1) >> 1;
    int g1 = (npairs * OUT_C + 255) / 256;

    if (ws_size >= total_pk) {
        int* flag = (int*)d_ws;
        u16* y    = (u16*)((char*)d_ws + o_y);
        u16* bufA = (u16*)((char*)d_ws + o_bufA);
        u16* bufB = (u16*)((char*)d_ws + o_bufB);
        // bf16 accumulator zeroing is folded into k_stage1's tail blocks
        size_t zero_bytes = a256(buf_bytes) + a256(buf_bytes);      // contiguous region
        int zcnt = (int)(zero_bytes / 16);
        int gz = (zcnt + 255) / 256;
        k_stage1<<<g1 + gz, 256, 0, stream>>>(x, W, ei, E, y, out, flag, n_nodes,
                                              g1, (uint4*)((char*)d_ws + o_bufA), zcnt);
        long long half = (E + 1) >> 1;
        long long t2 = half * 8;
        k_stage2_pk<<<(int)((t2 + 255) / 256), 256, 0, stream>>>(ei, ea, y, bufA, bufB, flag, E);
        int t3 = (n_nodes * OUT_C) / 8;
        k_final_pk<<<(t3 + 255) / 256, 256, 0, stream>>>(bufA, bufB, bias, out, t3);
    } else if (ws_size >= 256 + y_bytes) {
        // R6-proven fallback: f32 atomics into d_out
        int* flag = (int*)d_ws;
        u16* y    = (u16*)((char*)d_ws + o_y);
        k_stage1<<<g1, 256, 0, stream>>>(x, W, ei, E, y, out, flag, n_nodes,
                                         g1, (uint4*)nullptr, 0);
        long long tE = E * OUT_C;
        k_stage2<<<(int)((tE + 255) / 256), 256, 0, stream>>>(ei, ea, y, out, flag, E);
        int t4 = (n_nodes * OUT_C) / 4;
        k_bias_relu<<<(t4 + 255) / 256, 256, 0, stream>>>(bias, out, t4);
    } else {
        hipMemsetAsync(d_out, 0, (size_t)n_nodes * OUT_C * sizeof(float), stream);
        long long tE = E * OUT_C;
        k_direct<<<(int)((tE + 255) / 256), 256, 0, stream>>>(x, ei, ea, W, out, E);
        int t4 = (n_nodes * OUT_C) / 4;
        k_bias_relu<<<(t4 + 255) / 256, 256, 0, stream>>>(bias, out, t4);
    }
}

// Round 3
// 198.886 us; speedup vs baseline: 1.0442x; 1.0442x over previous
//
#include <hip/hip_runtime.h>

// CustomGraphConv (fp32 in/out, int64 edge_index runtime-detected):
//   msg[e,o] = sum_{a,i} ea[e,a]*W[a,o,i]*x[src_e,i]; scatter-add to dst; relu(+bias).
//
// R3 structure. Measured R0-R2: stage2 pins at ~2.85 TB/s L2<->fabric traffic
// (253 MB / 89 us); nt-hints and ILP both null => byte-bound, not latency-bound.
// Per-XCD L2 is 4 MB non-shared, so the 25.6 MB bf16 y-table re-fetches ~100 MB.
//   stage1: y8[n][o][a] = uint8 quant of sum_i W[a,o,i]*x[n,i], per-NODE scale
//           stab[n] (f32). One 128 B line per node (was 256 B bf16).
//           Cross-lane max over the 16 lanes sharing a node-pair via shfl_xor.
//           Tail blocks zero the two bf16 accumulators (memset folded in).
//   stage2: 8 lanes/edge; lane q decodes channels {2q,2q+1} from one uint4
//           (16 B of u8), dot vs ea in f32 (cvt_f32_ubyte+fma, -128*sum(ea)
//           fixup), packs bf16x2, ONE global_atomic_pk_add_bf16 -> 12.8M ops.
//           Edge-parity split across two bf16 buffers halves the rounding walk.
//   final:  out = relu(f32(bufA) + f32(bufB) + bias).

#define IN_C 16
#define OUT_C 16
#define NA 8

typedef unsigned short u16;
typedef unsigned int u32;
typedef unsigned char u8;
typedef short v2s __attribute__((ext_vector_type(2)));
typedef float v4f __attribute__((ext_vector_type(4)));

__device__ __forceinline__ float bfbits(u32 hi) {
    union { u32 u; float f; } c; c.u = hi; return c.f;
}
__device__ __forceinline__ u16 f2bf(float f) {
    union { float f; u32 u; } c; c.f = f;
    u32 u = c.u + (0x7fffu + ((c.u >> 16) & 1u));   // RNE
    return (u16)(u >> 16);
}
__device__ __forceinline__ float dot4(float4 a, float4 b) {
    float s = a.x * b.x;
    s = fmaf(a.y, b.y, s); s = fmaf(a.z, b.z, s); s = fmaf(a.w, b.w, s);
    return s;
}
// dot of 8 biased-uint8 (two dwords) against ea[0..7]; caller applies s*(d-128*sumea)
__device__ __forceinline__ float dotu8(u32 w0, u32 w1, v4f a0, v4f a1) {
    float s = (float)(w0 & 255u) * a0.x;
    s = fmaf((float)((w0 >> 8) & 255u),  a0.y, s);
    s = fmaf((float)((w0 >> 16) & 255u), a0.z, s);
    s = fmaf((float)(w0 >> 24),          a0.w, s);
    s = fmaf((float)(w1 & 255u),         a1.x, s);
    s = fmaf((float)((w1 >> 8) & 255u),  a1.y, s);
    s = fmaf((float)((w1 >> 16) & 255u), a1.z, s);
    s = fmaf((float)(w1 >> 24),          a1.w, s);
    return s;
}
__device__ __forceinline__ u32 pack4(const float* v, float r) {
    u32 w = 0;
#pragma unroll
    for (int k = 0; k < 4; ++k) {
        int q = (int)rintf(v[k] * r) + 128;
        q = q < 0 ? 0 : (q > 255 ? 255 : q);
        w |= ((u32)q) << (8 * k);
    }
    return w;
}

// ---------- stage 1: per-node u8 quant of y[n,o,a] + f32 scale table;
//            zeroes out[]; block 0 detects int64; tail blocks zero the
//            bf16 accumulators (replaces hipMemsetAsync dispatch) ----------
__global__ void __launch_bounds__(256) k_stage1(
    const float* __restrict__ x, const float* __restrict__ W,
    const int* __restrict__ ei, long long n_edges,
    u8* __restrict__ y8, float* __restrict__ stab, float* __restrict__ out,
    int* __restrict__ flag, int n_nodes,
    int main_blocks, uint4* __restrict__ zbase, int zcnt) {
    if ((int)blockIdx.x >= main_blocks) {
        int zi = ((int)blockIdx.x - main_blocks) * 256 + (int)threadIdx.x;
        if (zi < zcnt) { uint4 z; z.x = z.y = z.z = z.w = 0u; zbase[zi] = z; }
        return;
    }
    __shared__ int s_nz;
    if (blockIdx.x == 0) {
        if (threadIdx.x == 0) s_nz = 0;
        __syncthreads();
        long long step = (n_edges / 256) | 1;
        long long pos = 1 + 2 * (long long)threadIdx.x * step;
        if (pos < 2 * n_edges && ei[pos] != 0) atomicOr(&s_nz, 1);
        __syncthreads();
        if (threadIdx.x == 0) flag[0] = (s_nz == 0) ? 1 : 0;   // 1 => int64
    }
    __shared__ float4 Wl[OUT_C][33];
    for (int k = threadIdx.x; k < 512; k += 256) {
        int a = k >> 6, o = (k >> 2) & 15, q = k & 3;
        Wl[o][a * 4 + q] = reinterpret_cast<const float4*>(W)[k];
    }
    __syncthreads();
    int npairs = (n_nodes + 1) >> 1;
    int idx = blockIdx.x * 256 + threadIdx.x;
    if (idx >= npairs * OUT_C) return;
    int p = idx >> 4, o = idx & 15;     // 16 consecutive lanes share a node pair
    int n0 = p * 2;
    bool has1 = (n0 + 1) < n_nodes;
    const float4* xp0 = reinterpret_cast<const float4*>(x + (size_t)n0 * IN_C);
    float4 X0[4] = {xp0[0], xp0[1], xp0[2], xp0[3]};
    float4 X1[4];
    if (has1) {
        const float4* xp1 = reinterpret_cast<const float4*>(x + (size_t)(n0 + 1) * IN_C);
        X1[0] = xp1[0]; X1[1] = xp1[1]; X1[2] = xp1[2]; X1[3] = xp1[3];
    }
    float v0[NA], v1[NA];
#pragma unroll
    for (int a = 0; a < NA; ++a) {
        float4 w0 = Wl[o][a * 4 + 0], w1 = Wl[o][a * 4 + 1];
        float4 w2 = Wl[o][a * 4 + 2], w3 = Wl[o][a * 4 + 3];
        v0[a] = dot4(w0, X0[0]) + dot4(w1, X0[1]) + dot4(w2, X0[2]) + dot4(w3, X0[3]);
        v1[a] = has1 ? (dot4(w0, X1[0]) + dot4(w1, X1[1]) + dot4(w2, X1[2]) + dot4(w3, X1[3]))
                     : 0.f;
    }
    // per-node max over all 16 o x 8 a values: local max then 16-lane reduce
    float m0 = 0.f, m1 = 0.f;
#pragma unroll
    for (int a = 0; a < NA; ++a) {
        m0 = fmaxf(m0, fabsf(v0[a]));
        m1 = fmaxf(m1, fabsf(v1[a]));
    }
#pragma unroll
    for (int w = 1; w < 16; w <<= 1) {
        m0 = fmaxf(m0, __shfl_xor(m0, w));
        m1 = fmaxf(m1, __shfl_xor(m1, w));
    }
    float r0 = m0 > 0.f ? 127.f / m0 : 0.f;
    float r1 = m1 > 0.f ? 127.f / m1 : 0.f;
    uint2 q0; q0.x = pack4(v0, r0); q0.y = pack4(v0 + 4, r0);
    reinterpret_cast<uint2*>(y8 + (size_t)n0 * 128 + o * 8)[0] = q0;
    out[(size_t)n0 * OUT_C + o] = 0.f;
    if (o == 0) stab[n0] = m0 * (1.f / 127.f);
    if (has1) {
        uint2 q1; q1.x = pack4(v1, r1); q1.y = pack4(v1 + 4, r1);
        reinterpret_cast<uint2*>(y8 + (size_t)(n0 + 1) * 128 + o * 8)[0] = q1;
        out[(size_t)(n0 + 1) * OUT_C + o] = 0.f;
        if (o == 0) stab[n0 + 1] = m1 * (1.f / 127.f);
    }
}

// ---------- stage 2 (pk-bf16): 8 lanes/edge, lane q -> channels 2q,2q+1,
//            u8 y decode (one 16B load/lane = 128B/edge, one L2 line),
//            one packed-bf16 atomic per lane; edge-parity buffer split ----------
__global__ void __launch_bounds__(256) k_stage2_pk(
    const int* __restrict__ ei, const float* __restrict__ ea,
    const u8* __restrict__ y8, const float* __restrict__ stab,
    u16* __restrict__ bufA, u16* __restrict__ bufB,
    const int* __restrict__ flag, long long n_edges) {
    long long gid = (long long)blockIdx.x * 256 + threadIdx.x;
    if (gid >= n_edges * 8) return;
    long long e = gid >> 3;
    int q = (int)(gid & 7);          // channel pair: 2q, 2q+1
    int src, dst;
    if (flag[0]) { src = ei[2 * e]; dst = ei[2 * (n_edges + e)]; }
    else         { src = ei[e];     dst = ei[n_edges + e]; }

    const v4f* ap = reinterpret_cast<const v4f*>(ea + e * NA);
    v4f a0 = ap[0], a1 = ap[1];
    float sumea = ((a0.x + a0.y) + (a0.z + a0.w)) + ((a1.x + a1.y) + (a1.z + a1.w));
    float s = stab[src];

    // 16 B of u8: channels 2q (yq.x,yq.y) and 2q+1 (yq.z,yq.w); 8 lanes tile the 128 B row
    uint4 yq = reinterpret_cast<const uint4*>(y8 + (size_t)src * 128 + q * 16)[0];
    float fix = -128.f * sumea;
    float s0 = s * (dotu8(yq.x, yq.y, a0, a1) + fix);
    float s1 = s * (dotu8(yq.z, yq.w, a0, a1) + fix);

    union { v2s v; u16 h[2]; } pk;
    pk.h[0] = f2bf(s0);
    pk.h[1] = f2bf(s1);
    u16* target = (e & 1) ? bufB : bufA;
    v2s* addr = reinterpret_cast<v2s*>(target + (size_t)dst * OUT_C + 2 * q);
    __builtin_amdgcn_global_atomic_fadd_v2bf16(addr, pk.v);
}

// ---------- final (pk path): out = relu(f32(bufA)+f32(bufB)+bias), 8 ch/thread ----------
__global__ void __launch_bounds__(256) k_final_pk(
    const u16* __restrict__ bufA, const u16* __restrict__ bufB,
    const float* __restrict__ bias, float* __restrict__ out, int total8) {
    int idx = blockIdx.x * 256 + threadIdx.x;
    if (idx >= total8) return;
    uint4 ua = reinterpret_cast<const uint4*>(bufA)[idx];
    uint4 ub = reinterpret_cast<const uint4*>(bufB)[idx];
    int ob = (idx & 1) * 8;
    const float4 b0 = reinterpret_cast<const float4*>(bias + ob)[0];
    const float4 b1 = reinterpret_cast<const float4*>(bias + ob + 4)[0];
    float fa[8], fb[8];
    u32 au[4] = {ua.x, ua.y, ua.z, ua.w}, bu[4] = {ub.x, ub.y, ub.z, ub.w};
#pragma unroll
    for (int j = 0; j < 4; ++j) {
        fa[2 * j]     = bfbits(au[j] << 16);
        fa[2 * j + 1] = bfbits(au[j] & 0xffff0000u);
        fb[2 * j]     = bfbits(bu[j] << 16);
        fb[2 * j + 1] = bfbits(bu[j] & 0xffff0000u);
    }
    float bb[8] = {b0.x, b0.y, b0.z, b0.w, b1.x, b1.y, b1.z, b1.w};
    float4 o0, o1;
    o0.x = fmaxf(fa[0] + fb[0] + bb[0], 0.f);
    o0.y = fmaxf(fa[1] + fb[1] + bb[1], 0.f);
    o0.z = fmaxf(fa[2] + fb[2] + bb[2], 0.f);
    o0.w = fmaxf(fa[3] + fb[3] + bb[3], 0.f);
    o1.x = fmaxf(fa[4] + fb[4] + bb[4], 0.f);
    o1.y = fmaxf(fa[5] + fb[5] + bb[5], 0.f);
    o1.z = fmaxf(fa[6] + fb[6] + bb[6], 0.f);
    o1.w = fmaxf(fa[7] + fb[7] + bb[7], 0.f);
    float4* op = reinterpret_cast<float4*>(out) + (size_t)idx * 2;
    op[0] = o0;
    op[1] = o1;
}

// ---------- fallback stage 2: 16 lanes/edge, u8 decode, f32 atomics ----------
__global__ void __launch_bounds__(256) k_stage2(
    const int* __restrict__ ei, const float* __restrict__ ea,
    const u8* __restrict__ y8, const float* __restrict__ stab,
    float* __restrict__ out, const int* __restrict__ flag, long long n_edges) {
    long long idx = (long long)blockIdx.x * 256 + threadIdx.x;
    if (idx >= n_edges * OUT_C) return;
    long long e = idx >> 4;
    int o = (int)(idx & 15);
    int src, dst;
    if (flag[0]) { src = ei[2 * e]; dst = ei[2 * (n_edges + e)]; }
    else         { src = ei[e];     dst = ei[n_edges + e]; }
    const v4f* ap = reinterpret_cast<const v4f*>(ea + e * NA);
    v4f a0 = ap[0], a1 = ap[1];
    float sumea = ((a0.x + a0.y) + (a0.z + a0.w)) + ((a1.x + a1.y) + (a1.z + a1.w));
    float sc = stab[src];
    uint2 yq = reinterpret_cast<const uint2*>(y8 + (size_t)src * 128 + o * 8)[0];
    float s = sc * (dotu8(yq.x, yq.y, a0, a1) - 128.f * sumea);
    unsafeAtomicAdd(out + (size_t)dst * OUT_C + o, s);
}

__global__ void __launch_bounds__(256) k_bias_relu(
    const float* __restrict__ bias, float* __restrict__ out, int total4) {
    int idx = blockIdx.x * 256 + threadIdx.x;
    if (idx >= total4) return;
    int j0 = (idx & 3) * 4;
    const float4 b = reinterpret_cast<const float4*>(bias + j0)[0];
    float4* op = reinterpret_cast<float4*>(out) + idx;
    float4 v = op[0];
    v.x = fmaxf(v.x + b.x, 0.f);
    v.y = fmaxf(v.y + b.y, 0.f);
    v.z = fmaxf(v.z + b.z, 0.f);
    v.w = fmaxf(v.w + b.w, 0.f);
    op[0] = v;
}

// ---------- ultimate fallback (tiny ws): direct einsum, f32 atomics ----------
__global__ void __launch_bounds__(256) k_direct(
    const float* __restrict__ x, const int* __restrict__ ei,
    const float* __restrict__ ea, const float* __restrict__ W,
    float* __restrict__ out, long long n_edges) {
    __shared__ float Wl[OUT_C][129];
    for (int k = threadIdx.x; k < NA * OUT_C * IN_C; k += 256) {
        int a = k >> 8, o = (k >> 4) & 15, i = k & 15;
        Wl[o][a * IN_C + i] = W[k];
    }
    __syncthreads();
    long long idx = (long long)blockIdx.x * 256 + threadIdx.x;
    if (idx >= n_edges * OUT_C) return;
    long long e = idx >> 4;
    int o = (int)(idx & 15);
    int src = ei[2 * e], dst = ei[2 * (n_edges + e)];
    const float4* ap = reinterpret_cast<const float4*>(ea + e * NA);
    float4 a0 = ap[0], a1 = ap[1];
    float av[NA] = {a0.x, a0.y, a0.z, a0.w, a1.x, a1.y, a1.z, a1.w};
    const float4* xp = reinterpret_cast<const float4*>(x + (size_t)src * IN_C);
    float4 x0 = xp[0], x1 = xp[1], x2 = xp[2], x3 = xp[3];
    float xv[16] = {x0.x, x0.y, x0.z, x0.w, x1.x, x1.y, x1.z, x1.w,
                    x2.x, x2.y, x2.z, x2.w, x3.x, x3.y, x3.z, x3.w};
    float s = 0.f;
#pragma unroll
    for (int a = 0; a < NA; ++a) {
        float d = 0.f;
#pragma unroll
        for (int i = 0; i < IN_C; ++i) d = fmaf(Wl[o][a * IN_C + i], xv[i], d);
        s = fmaf(av[a], d, s);
    }
    unsafeAtomicAdd(out + (size_t)dst * OUT_C + o, s);
}

static inline size_t a256(size_t v) { return (v + 255) & ~(size_t)255; }

extern "C" void kernel_launch(void* const* d_in, const int* in_sizes, int n_in,
                              void* d_out, int out_size, void* d_ws, size_t ws_size,
                              hipStream_t stream) {
    const float* x    = (const float*)d_in[0];   // [N,16] f32
    const int*   ei   = (const int*)d_in[1];     // [2,E] int64/int32 (runtime-detected)
    const float* ea   = (const float*)d_in[2];   // [E,8] f32
    const float* W    = (const float*)d_in[3];   // [8,16,16] f32
    const float* bias = (const float*)d_in[4];   // [16] f32
    float* out = (float*)d_out;

    int n_nodes = in_sizes[0] / IN_C;
    long long E = in_sizes[2] / NA;

    size_t o_stab = 256;
    size_t stab_bytes = (size_t)n_nodes * sizeof(float);            // 0.4 MB
    size_t o_y    = o_stab + a256(stab_bytes);
    size_t y_bytes = (size_t)n_nodes * 128;                         // 12.8 MB (u8)
    size_t o_bufA = o_y + a256(y_bytes);
    size_t buf_bytes = (size_t)n_nodes * OUT_C * sizeof(u16);       // 3.2 MB each
    size_t o_bufB = o_bufA + a256(buf_bytes);
    size_t total_pk = o_bufB + a256(buf_bytes);                     // ~19.9 MB

    int npairs = (n_nodes + 1) >> 1;
    int g1 = (npairs * OUT_C + 255) / 256;

    if (ws_size >= total_pk) {
        int* flag  = (int*)d_ws;
        float* stab = (float*)((char*)d_ws + o_stab);
        u8*  y8   = (u8*)((char*)d_ws + o_y);
        u16* bufA = (u16*)((char*)d_ws + o_bufA);
        u16* bufB = (u16*)((char*)d_ws + o_bufB);
        // bf16 accumulator zeroing folded into k_stage1's tail blocks
        size_t zero_bytes = a256(buf_bytes) + a256(buf_bytes);      // contiguous region
        int zcnt = (int)(zero_bytes / 16);
        int gz = (zcnt + 255) / 256;
        k_stage1<<<g1 + gz, 256, 0, stream>>>(x, W, ei, E, y8, stab, out, flag, n_nodes,
                                              g1, (uint4*)((char*)d_ws + o_bufA), zcnt);
        long long t2 = E * 8;
        k_stage2_pk<<<(int)((t2 + 255) / 256), 256, 0, stream>>>(ei, ea, y8, stab,
                                                                 bufA, bufB, flag, E);
        int t3 = (n_nodes * OUT_C) / 8;
        k_final_pk<<<(t3 + 255) / 256, 256, 0, stream>>>(bufA, bufB, bias, out, t3);
    } else if (ws_size >= o_y + y_bytes) {
        // fallback: f32 atomics into d_out
        int* flag  = (int*)d_ws;
        float* stab = (float*)((char*)d_ws + o_stab);
        u8*  y8   = (u8*)((char*)d_ws + o_y);
        k_stage1<<<g1, 256, 0, stream>>>(x, W, ei, E, y8, stab, out, flag, n_nodes,
                                         g1, (uint4*)nullptr, 0);
        long long tE = E * OUT_C;
        k_stage2<<<(int)((tE + 255) / 256), 256, 0, stream>>>(ei, ea, y8, stab, out, flag, E);
        int t4 = (n_nodes * OUT_C) / 4;
        k_bias_relu<<<(t4 + 255) / 256, 256, 0, stream>>>(bias, out, t4);
    } else {
        hipMemsetAsync(d_out, 0, (size_t)n_nodes * OUT_C * sizeof(float), stream);
        long long tE = E * OUT_C;
        k_direct<<<(int)((tE + 255) / 256), 256, 0, stream>>>(x, ei, ea, W, out, E);
        int t4 = (n_nodes * OUT_C) / 4;
        k_bias_relu<<<(t4 + 255) / 256, 256, 0, stream>>>(bias, out, t4);
    }
}